// Round 6
// baseline (1364.672 us; speedup 1.0000x reference)
//
#include <hip/hip_runtime.h>
#include <math.h>

#define IN_DIM 256
#define HID 48
#define CLS 16
#define K_STEPS 10
#define ALPHA 0.1f

// ---------------- utility ----------------

__global__ void zero_int_kernel(int* __restrict__ p, int n) {
    int i = blockIdx.x * blockDim.x + threadIdx.x;
    if (i < n) p[i] = 0;
}

__global__ void hist_kernel(const int* __restrict__ dst, int* __restrict__ deg, int nE) {
    int i = blockIdx.x * blockDim.x + threadIdx.x;
    if (i < nE) atomicAdd(&deg[dst[i]], 1);
}

__global__ void norm_kernel(const int* __restrict__ deg, float* __restrict__ nrm, int n) {
    int i = blockIdx.x * blockDim.x + threadIdx.x;
    if (i < n) nrm[i] = rsqrtf(fmaxf((float)deg[i], 1.0f));
}

// ---------------- exclusive scan over deg -> off, cursor ----------------

__global__ __launch_bounds__(256) void scan1_kernel(const int* __restrict__ deg,
                                                    int* __restrict__ bsum, int n) {
    __shared__ int ls[256];
    int t = threadIdx.x;
    int base = blockIdx.x * 1024 + t * 4;
    int s = 0;
    if (base + 3 < n) {
        int4 d = *(const int4*)(deg + base);
        s = d.x + d.y + d.z + d.w;
    } else {
        for (int i = 0; i < 4; i++) if (base + i < n) s += deg[base + i];
    }
    ls[t] = s; __syncthreads();
    for (int o = 128; o > 0; o >>= 1) {
        if (t < o) ls[t] += ls[t + o];
        __syncthreads();
    }
    if (t == 0) bsum[blockIdx.x] = ls[0];
}

__global__ void scan2_kernel(int* __restrict__ bsum, int* __restrict__ off, int nb, int n) {
    if (threadIdx.x == 0 && blockIdx.x == 0) {
        int run = 0;
        for (int i = 0; i < nb; i++) { int t = bsum[i]; bsum[i] = run; run += t; }
        off[n] = run;
    }
}

__global__ __launch_bounds__(256) void scan3_kernel(const int* __restrict__ deg,
                                                    const int* __restrict__ bsum,
                                                    int* __restrict__ off,
                                                    int* __restrict__ cursor, int n) {
    __shared__ int ts[256];
    int t = threadIdx.x;
    int base = blockIdx.x * 1024 + t * 4;
    int d0 = 0, d1 = 0, d2 = 0, d3 = 0;
    if (base + 3 < n) {
        int4 d = *(const int4*)(deg + base);
        d0 = d.x; d1 = d.y; d2 = d.z; d3 = d.w;
    } else {
        if (base     < n) d0 = deg[base];
        if (base + 1 < n) d1 = deg[base + 1];
        if (base + 2 < n) d2 = deg[base + 2];
        if (base + 3 < n) d3 = deg[base + 3];
    }
    int s = d0 + d1 + d2 + d3;
    ts[t] = s; __syncthreads();
    for (int o = 1; o < 256; o <<= 1) {
        int v = (t >= o) ? ts[t - o] : 0;
        __syncthreads();
        ts[t] += v;
        __syncthreads();
    }
    int ex = ts[t] - s + bsum[blockIdx.x];
    int p0 = ex, p1 = ex + d0, p2 = p1 + d1, p3 = p2 + d2;
    if (base     < n) { off[base]     = p0; cursor[base]     = p0; }
    if (base + 1 < n) { off[base + 1] = p1; cursor[base + 1] = p1; }
    if (base + 2 < n) { off[base + 2] = p2; cursor[base + 2] = p2; }
    if (base + 3 < n) { off[base + 3] = p3; cursor[base + 3] = p3; }
}

__global__ void fill_kernel(const int* __restrict__ src, const int* __restrict__ dst,
                            int* __restrict__ cursor, int* __restrict__ csrc, int nE) {
    int e = blockIdx.x * blockDim.x + threadIdx.x;
    if (e >= nE) return;
    int p = atomicAdd(&cursor[dst[e]], 1);
    csrc[p] = src[e];
}

// ---------------- degree-sorted node permutation (counting sort, 64 buckets) ----

__global__ void bucket_count_kernel(const int* __restrict__ deg, int* __restrict__ bcnt, int n) {
    int i = blockIdx.x * blockDim.x + threadIdx.x;
    if (i < n) atomicAdd(&bcnt[min(deg[i], 63)], 1);
}

__global__ void bucket_scan_kernel(int* __restrict__ bcnt, int* __restrict__ bcur) {
    if (threadIdx.x == 0 && blockIdx.x == 0) {
        int run = 0;
        for (int b = 0; b < 64; b++) { int c = bcnt[b]; bcur[b] = run; run += c; }
    }
}

__global__ void bucket_fill_kernel(const int* __restrict__ deg, int* __restrict__ bcur,
                                   int* __restrict__ perm, int n) {
    int i = blockIdx.x * blockDim.x + threadIdx.x;
    if (i < n) {
        int p = atomicAdd(&bcur[min(deg[i], 63)], 1);
        perm[p] = i;
    }
}

// ---------------- Wc = W2 @ W1 [16,256], bc = W2 @ b1 [16] ----------------

__global__ __launch_bounds__(256) void wc_kernel(
    const float* __restrict__ W1, const float* __restrict__ W2,
    const float* __restrict__ b1, float* __restrict__ Wc, float* __restrict__ bc)
{
    int c = blockIdx.x;         // 0..15
    int k = threadIdx.x;        // 0..255
    float acc = 0.0f;
    #pragma unroll
    for (int j = 0; j < HID; j++)
        acc = fmaf(W2[c * HID + j], W1[j * IN_DIM + k], acc);
    Wc[c * IN_DIM + k] = acc;
    if (k == 0) {
        float b = 0.0f;
        for (int j = 0; j < HID; j++) b = fmaf(W2[c * HID + j], b1[j], b);
        bc[c] = b;
    }
}

// ---------------- fused fc: z0 = X @ Wc^T + bc; A = z0*nrm ----------------

#define BM 128
#define BK 16
__global__ __launch_bounds__(256) void fcz_kernel(
    const float* __restrict__ X, const float* __restrict__ Wc,
    const float* __restrict__ bc, const float* __restrict__ nrm,
    float* __restrict__ z0, float* __restrict__ A, int n)
{
    __shared__ float Xs[BK][BM + 1];
    __shared__ float Ws[BK][CLS];
    const int t = threadIdx.x;
    const int tx = t & 31;
    const int ty = t >> 5;            // 0..7, owns 2 outputs
    const int mbase = blockIdx.x * BM;
    float acc[4][2] = {{0}};

    for (int k0 = 0; k0 < IN_DIM; k0 += BK) {
        #pragma unroll
        for (int c0 = 0; c0 < 2; c0++) {
            int c = t + c0 * 256;
            int m = c >> 2, kc = (c & 3) << 2;
            int gm = mbase + m;
            float4 xv = make_float4(0.f, 0.f, 0.f, 0.f);
            if (gm < n) xv = *(const float4*)(X + (size_t)gm * IN_DIM + k0 + kc);
            Xs[kc + 0][m] = xv.x; Xs[kc + 1][m] = xv.y;
            Xs[kc + 2][m] = xv.z; Xs[kc + 3][m] = xv.w;
        }
        if (t < 64) {
            int j = t >> 2, kc = (t & 3) << 2;
            float4 wv = *(const float4*)(Wc + (size_t)j * IN_DIM + k0 + kc);
            Ws[kc + 0][j] = wv.x; Ws[kc + 1][j] = wv.y;
            Ws[kc + 2][j] = wv.z; Ws[kc + 3][j] = wv.w;
        }
        __syncthreads();
        #pragma unroll
        for (int k = 0; k < BK; k++) {
            float a[4], b[2];
            #pragma unroll
            for (int im = 0; im < 4; im++) a[im] = Xs[k][tx + 32 * im];
            #pragma unroll
            for (int jn = 0; jn < 2; jn++) b[jn] = Ws[k][ty * 2 + jn];
            #pragma unroll
            for (int im = 0; im < 4; im++)
                #pragma unroll
                for (int jn = 0; jn < 2; jn++)
                    acc[im][jn] = fmaf(a[im], b[jn], acc[im][jn]);
        }
        __syncthreads();
    }

    #pragma unroll
    for (int im = 0; im < 4; im++) {
        int m = mbase + tx + 32 * im;
        if (m < n) {
            float nv = nrm[m];
            #pragma unroll
            for (int jn = 0; jn < 2; jn++) {
                int j = ty * 2 + jn;
                float r = acc[im][jn] + bc[j];
                size_t idx = (size_t)m * CLS + j;
                z0[idx] = r;
                A[idx] = r * nv;
            }
        }
    }
}

// ---------------- pull gather + fused combine (D=16, 16 lanes/node) ----------------
// Nodes processed in degree-sorted order (perm): all 4 nodes of a wave share
// ~the same degree -> uniform trip counts, no exec-mask waste.
// MODE 0: outp=r*nrm; MODE 1: x=elu(r+b2), out2=x, outp=x*nrm; MODE 2: outp=elu(r).

__device__ __forceinline__ void f4add(float4& a, const float4& b) {
    a.x += b.x; a.y += b.y; a.z += b.z; a.w += b.w;
}
__device__ __forceinline__ float eluf(float x) {
    return x > 0.0f ? x : expm1f(x);
}

template<int MODE>
__global__ __launch_bounds__(256) void gather16_kernel(
    const int* __restrict__ perm,
    const int* __restrict__ off, const int* __restrict__ csrc,
    const float4* __restrict__ A, const float4* __restrict__ tele,
    const float* __restrict__ nrm, const float4* __restrict__ b2v,
    float4* __restrict__ outp, float4* __restrict__ out2, int n)
{
    const int t = threadIdx.x;
    const int g = blockIdx.x * 16 + (t >> 4);
    if (g >= n) return;
    const int v = perm[g];
    const int lane = t & 3;          // float4 lane within node row
    const int way  = (t >> 2) & 3;   // edge way

    const int s = off[v], e = off[v + 1];
    float4 a0 = make_float4(0.f, 0.f, 0.f, 0.f), a1 = a0;
    int i = s + way;
    for (; i + 4 < e; i += 8) {
        int u0 = csrc[i], u1 = csrc[i + 4];
        float4 v0 = A[(size_t)u0 * 4 + lane];
        float4 v1 = A[(size_t)u1 * 4 + lane];
        f4add(a0, v0); f4add(a1, v1);
    }
    for (; i < e; i += 4) f4add(a0, A[(size_t)csrc[i] * 4 + lane]);
    f4add(a0, a1);

    // cross-way reduce (xor bits 2,3 of tid; stays within this node's 16 lanes)
    a0.x += __shfl_xor(a0.x, 4); a0.y += __shfl_xor(a0.y, 4);
    a0.z += __shfl_xor(a0.z, 4); a0.w += __shfl_xor(a0.w, 4);
    a0.x += __shfl_xor(a0.x, 8); a0.y += __shfl_xor(a0.y, 8);
    a0.z += __shfl_xor(a0.z, 8); a0.w += __shfl_xor(a0.w, 8);

    if (way != 0) return;

    float nv = nrm[v];
    size_t o = (size_t)v * 4 + lane;
    float4 hv = tele[o];
    float4 r;
    r.x = (1.0f - ALPHA) * a0.x * nv + ALPHA * hv.x;
    r.y = (1.0f - ALPHA) * a0.y * nv + ALPHA * hv.y;
    r.z = (1.0f - ALPHA) * a0.z * nv + ALPHA * hv.z;
    r.w = (1.0f - ALPHA) * a0.w * nv + ALPHA * hv.w;
    if (MODE == 0) {
        outp[o] = make_float4(r.x * nv, r.y * nv, r.z * nv, r.w * nv);
    } else if (MODE == 1) {
        float4 b = b2v[lane];
        float4 x;
        x.x = eluf(r.x + b.x); x.y = eluf(r.y + b.y);
        x.z = eluf(r.z + b.z); x.w = eluf(r.w + b.w);
        out2[o] = x;
        outp[o] = make_float4(x.x * nv, x.y * nv, x.z * nv, x.w * nv);
    } else {
        outp[o] = make_float4(eluf(r.x), eluf(r.y), eluf(r.z), eluf(r.w));
    }
}

// ---------------- launch ----------------

extern "C" void kernel_launch(void* const* d_in, const int* in_sizes, int n_in,
                              void* d_out, int out_size, void* d_ws, size_t ws_size,
                              hipStream_t stream)
{
    const float* features = (const float*)d_in[0];
    const int*   src      = (const int*)d_in[1];
    const int*   dst      = (const int*)d_in[2];
    const float* W1       = (const float*)d_in[3];
    const float* b1       = (const float*)d_in[4];
    const float* W2       = (const float*)d_in[5];
    const float* b2       = (const float*)d_in[6];
    float* out = (float*)d_out;

    const int n  = in_sizes[0] / IN_DIM;   // 100000
    const int nE = in_sizes[1];            // 1600000

    // workspace: floats nrm[n] | z0[16n] | P[16n] | Q[16n] | x0[16n] | Wc[4096] | bc[16]
    //            ints   deg[n] | off[n+4] | cursor[n] | bsum[1024] | perm[n] | bcnt[64] | bcur[64] | csrc[nE]
    float* ws   = (float*)d_ws;
    float* nrm  = ws;
    float* z0   = nrm + n;
    float* P    = z0 + (size_t)CLS * n;
    float* Q    = P + (size_t)CLS * n;
    float* x0   = Q + (size_t)CLS * n;
    float* Wc   = x0 + (size_t)CLS * n;
    float* bc   = Wc + CLS * IN_DIM;
    int*   deg    = (int*)(bc + 16);
    int*   off    = deg + n;
    int*   cursor = off + n + 4;
    int*   bsum   = cursor + n;
    int*   perm   = bsum + 1024;
    int*   bcnt   = perm + n;
    int*   bcur   = bcnt + 64;
    int*   csrc   = bcur + 64;

    const int B = 256;
    const int nb = (n + 1023) / 1024;

    // ---- degree, norm, CSR ----
    zero_int_kernel<<<(n + B - 1) / B, B, 0, stream>>>(deg, n);
    hist_kernel<<<(nE + B - 1) / B, B, 0, stream>>>(dst, deg, nE);
    norm_kernel<<<(n + B - 1) / B, B, 0, stream>>>(deg, nrm, n);
    scan1_kernel<<<nb, 256, 0, stream>>>(deg, bsum, n);
    scan2_kernel<<<1, 64, 0, stream>>>(bsum, off, nb, n);
    scan3_kernel<<<nb, 256, 0, stream>>>(deg, bsum, off, cursor, n);
    fill_kernel<<<(nE + B - 1) / B, B, 0, stream>>>(src, dst, cursor, csrc, nE);

    // ---- degree-sorted permutation ----
    zero_int_kernel<<<1, 64, 0, stream>>>(bcnt, 64);
    bucket_count_kernel<<<(n + B - 1) / B, B, 0, stream>>>(deg, bcnt, n);
    bucket_scan_kernel<<<1, 64, 0, stream>>>(bcnt, bcur);
    bucket_fill_kernel<<<(n + B - 1) / B, B, 0, stream>>>(deg, bcur, perm, n);

    // ---- combined fc ----
    wc_kernel<<<CLS, 256, 0, stream>>>(W1, W2, b1, Wc, bc);
    fcz_kernel<<<(n + BM - 1) / BM, 256, 0, stream>>>(features, Wc, bc, nrm, z0, P, n);

    int ggrid = (n + 15) / 16;

    // ---- propagation 1 (teleport z0); last step fuses +b2, ELU ----
    float* pa = P; float* pb = Q;
    for (int k = 0; k < K_STEPS; k++) {
        if (k < K_STEPS - 1)
            gather16_kernel<0><<<ggrid, 256, 0, stream>>>(
                perm, off, csrc, (const float4*)pa, (const float4*)z0, nrm,
                nullptr, (float4*)pb, nullptr, n);
        else
            gather16_kernel<1><<<ggrid, 256, 0, stream>>>(
                perm, off, csrc, (const float4*)pa, (const float4*)z0, nrm,
                (const float4*)b2, (float4*)pb, (float4*)x0, n);
        float* t = pa; pa = pb; pb = t;
    }

    // ---- propagation 2 (teleport x0); last step fuses ELU -> out ----
    for (int k = 0; k < K_STEPS; k++) {
        if (k < K_STEPS - 1)
            gather16_kernel<0><<<ggrid, 256, 0, stream>>>(
                perm, off, csrc, (const float4*)pa, (const float4*)x0, nrm,
                nullptr, (float4*)pb, nullptr, n);
        else
            gather16_kernel<2><<<ggrid, 256, 0, stream>>>(
                perm, off, csrc, (const float4*)pa, (const float4*)x0, nrm,
                nullptr, (float4*)out, nullptr, n);
        float* t = pa; pa = pb; pb = t;
    }
}

// Round 7
// 610.645 us; speedup vs baseline: 2.2348x; 2.2348x over previous
//
#include <hip/hip_runtime.h>
#include <hip/hip_fp16.h>
#include <math.h>

#define IN_DIM 256
#define HID 48
#define CLS 16
#define K_STEPS 10
#define ALPHA 0.1f

// ---------------- utility ----------------

__global__ void zero_int_kernel(int* __restrict__ p, int n) {
    int i = blockIdx.x * blockDim.x + threadIdx.x;
    if (i < n) p[i] = 0;
}

__global__ void hist_kernel(const int* __restrict__ dst, int* __restrict__ deg, int nE) {
    int i = blockIdx.x * blockDim.x + threadIdx.x;
    if (i < nE) atomicAdd(&deg[dst[i]], 1);
}

__global__ void norm_kernel(const int* __restrict__ deg, float* __restrict__ nrm, int n) {
    int i = blockIdx.x * blockDim.x + threadIdx.x;
    if (i < n) nrm[i] = rsqrtf(fmaxf((float)deg[i], 1.0f));
}

// ---------------- exclusive scan over deg -> off, cursor ----------------

__global__ __launch_bounds__(256) void scan1_kernel(const int* __restrict__ deg,
                                                    int* __restrict__ bsum, int n) {
    __shared__ int ls[256];
    int t = threadIdx.x;
    int base = blockIdx.x * 1024 + t * 4;
    int s = 0;
    if (base + 3 < n) {
        int4 d = *(const int4*)(deg + base);
        s = d.x + d.y + d.z + d.w;
    } else {
        for (int i = 0; i < 4; i++) if (base + i < n) s += deg[base + i];
    }
    ls[t] = s; __syncthreads();
    for (int o = 128; o > 0; o >>= 1) {
        if (t < o) ls[t] += ls[t + o];
        __syncthreads();
    }
    if (t == 0) bsum[blockIdx.x] = ls[0];
}

__global__ void scan2_kernel(int* __restrict__ bsum, int* __restrict__ off, int nb, int n) {
    if (threadIdx.x == 0 && blockIdx.x == 0) {
        int run = 0;
        for (int i = 0; i < nb; i++) { int t = bsum[i]; bsum[i] = run; run += t; }
        off[n] = run;
    }
}

__global__ __launch_bounds__(256) void scan3_kernel(const int* __restrict__ deg,
                                                    const int* __restrict__ bsum,
                                                    int* __restrict__ off,
                                                    int* __restrict__ cursor, int n) {
    __shared__ int ts[256];
    int t = threadIdx.x;
    int base = blockIdx.x * 1024 + t * 4;
    int d0 = 0, d1 = 0, d2 = 0, d3 = 0;
    if (base + 3 < n) {
        int4 d = *(const int4*)(deg + base);
        d0 = d.x; d1 = d.y; d2 = d.z; d3 = d.w;
    } else {
        if (base     < n) d0 = deg[base];
        if (base + 1 < n) d1 = deg[base + 1];
        if (base + 2 < n) d2 = deg[base + 2];
        if (base + 3 < n) d3 = deg[base + 3];
    }
    int s = d0 + d1 + d2 + d3;
    ts[t] = s; __syncthreads();
    for (int o = 1; o < 256; o <<= 1) {
        int v = (t >= o) ? ts[t - o] : 0;
        __syncthreads();
        ts[t] += v;
        __syncthreads();
    }
    int ex = ts[t] - s + bsum[blockIdx.x];
    int p0 = ex, p1 = ex + d0, p2 = p1 + d1, p3 = p2 + d2;
    if (base     < n) { off[base]     = p0; cursor[base]     = p0; }
    if (base + 1 < n) { off[base + 1] = p1; cursor[base + 1] = p1; }
    if (base + 2 < n) { off[base + 2] = p2; cursor[base + 2] = p2; }
    if (base + 3 < n) { off[base + 3] = p3; cursor[base + 3] = p3; }
}

__global__ void fill_kernel(const int* __restrict__ src, const int* __restrict__ dst,
                            int* __restrict__ cursor, int* __restrict__ csrc, int nE) {
    int e = blockIdx.x * blockDim.x + threadIdx.x;
    if (e >= nE) return;
    int p = atomicAdd(&cursor[dst[e]], 1);
    csrc[p] = src[e];
}

// ---------------- Wc = W2 @ W1 [16,256], bc = W2 @ b1 [16] ----------------

__global__ __launch_bounds__(256) void wc_kernel(
    const float* __restrict__ W1, const float* __restrict__ W2,
    const float* __restrict__ b1, float* __restrict__ Wc, float* __restrict__ bc)
{
    int c = blockIdx.x;         // 0..15
    int k = threadIdx.x;        // 0..255
    float acc = 0.0f;
    #pragma unroll
    for (int j = 0; j < HID; j++)
        acc = fmaf(W2[c * HID + j], W1[j * IN_DIM + k], acc);
    Wc[c * IN_DIM + k] = acc;
    if (k == 0) {
        float b = 0.0f;
        for (int j = 0; j < HID; j++) b = fmaf(W2[c * HID + j], b1[j], b);
        bc[c] = b;
    }
}

// ---------------- fused fc: z0 = X @ Wc^T + bc (f32); A = half(z0*nrm) ----------------

#define BM 128
#define BK 16
__global__ __launch_bounds__(256) void fcz_kernel(
    const float* __restrict__ X, const float* __restrict__ Wc,
    const float* __restrict__ bc, const float* __restrict__ nrm,
    float* __restrict__ z0, __half* __restrict__ A, int n)
{
    __shared__ float Xs[BK][BM + 1];
    __shared__ float Ws[BK][CLS];
    const int t = threadIdx.x;
    const int tx = t & 31;
    const int ty = t >> 5;            // 0..7, owns 2 consecutive outputs
    const int mbase = blockIdx.x * BM;
    float acc[4][2] = {{0}};

    for (int k0 = 0; k0 < IN_DIM; k0 += BK) {
        #pragma unroll
        for (int c0 = 0; c0 < 2; c0++) {
            int c = t + c0 * 256;
            int m = c >> 2, kc = (c & 3) << 2;
            int gm = mbase + m;
            float4 xv = make_float4(0.f, 0.f, 0.f, 0.f);
            if (gm < n) xv = *(const float4*)(X + (size_t)gm * IN_DIM + k0 + kc);
            Xs[kc + 0][m] = xv.x; Xs[kc + 1][m] = xv.y;
            Xs[kc + 2][m] = xv.z; Xs[kc + 3][m] = xv.w;
        }
        if (t < 64) {
            int j = t >> 2, kc = (t & 3) << 2;
            float4 wv = *(const float4*)(Wc + (size_t)j * IN_DIM + k0 + kc);
            Ws[kc + 0][j] = wv.x; Ws[kc + 1][j] = wv.y;
            Ws[kc + 2][j] = wv.z; Ws[kc + 3][j] = wv.w;
        }
        __syncthreads();
        #pragma unroll
        for (int k = 0; k < BK; k++) {
            float a[4], b[2];
            #pragma unroll
            for (int im = 0; im < 4; im++) a[im] = Xs[k][tx + 32 * im];
            #pragma unroll
            for (int jn = 0; jn < 2; jn++) b[jn] = Ws[k][ty * 2 + jn];
            #pragma unroll
            for (int im = 0; im < 4; im++)
                #pragma unroll
                for (int jn = 0; jn < 2; jn++)
                    acc[im][jn] = fmaf(a[im], b[jn], acc[im][jn]);
        }
        __syncthreads();
    }

    #pragma unroll
    for (int im = 0; im < 4; im++) {
        int m = mbase + tx + 32 * im;
        if (m < n) {
            float nv = nrm[m];
            float r0 = acc[im][0] + bc[ty * 2 + 0];
            float r1 = acc[im][1] + bc[ty * 2 + 1];
            size_t idx = (size_t)m * CLS + ty * 2;
            z0[idx] = r0;
            z0[idx + 1] = r1;
            ((__half2*)A)[(size_t)m * 8 + ty] = __floats2half2_rn(r0 * nv, r1 * nv);
        }
    }
}

// ---------------- pull gather + fused combine (D=16, half storage) ----------------
// A rows are 16 halves = 32 B; 4 lanes/node, each lane owns 4 halves (8 B load).
// Accumulation fp32. MODE 0: outp = half(r*nrm); MODE 1: x = elu(r+b2),
// x0 = x (f32 teleport), outp = half(x*nrm); MODE 2: outf = elu(r) (f32 out).

struct __align__(8) half4 { __half2 a, b; };

__device__ __forceinline__ void hacc(float4& acc, half4 w) {
    float2 lo = __half22float2(w.a);
    float2 hi = __half22float2(w.b);
    acc.x += lo.x; acc.y += lo.y; acc.z += hi.x; acc.w += hi.y;
}
__device__ __forceinline__ float eluf(float x) {
    return x > 0.0f ? x : expm1f(x);
}

template<int MODE>
__global__ __launch_bounds__(256) void gatherh_kernel(
    const int* __restrict__ off, const int* __restrict__ csrc,
    const half4* __restrict__ A, const float4* __restrict__ tele,
    const float* __restrict__ nrm, const float4* __restrict__ b2v,
    half4* __restrict__ outp, float4* __restrict__ x0out,
    float4* __restrict__ outf, int n)
{
    const int v = blockIdx.x * 64 + threadIdx.y;
    if (v >= n) return;
    const int lane = threadIdx.x;        // 0..3

    const int s = off[v], e = off[v + 1];
    float4 a0 = make_float4(0.f, 0.f, 0.f, 0.f), a1 = a0;
    int i = s;
    for (; i + 3 < e; i += 4) {
        int u0 = csrc[i], u1 = csrc[i + 1], u2 = csrc[i + 2], u3 = csrc[i + 3];
        half4 w0 = A[(size_t)u0 * 4 + lane];
        half4 w1 = A[(size_t)u1 * 4 + lane];
        half4 w2 = A[(size_t)u2 * 4 + lane];
        half4 w3 = A[(size_t)u3 * 4 + lane];
        hacc(a0, w0); hacc(a1, w1); hacc(a0, w2); hacc(a1, w3);
    }
    for (; i < e; i++) hacc(a0, A[(size_t)csrc[i] * 4 + lane]);
    a0.x += a1.x; a0.y += a1.y; a0.z += a1.z; a0.w += a1.w;

    float nv = nrm[v];
    size_t o = (size_t)v * 4 + lane;
    float4 hv = tele[o];
    float4 r;
    r.x = (1.0f - ALPHA) * a0.x * nv + ALPHA * hv.x;
    r.y = (1.0f - ALPHA) * a0.y * nv + ALPHA * hv.y;
    r.z = (1.0f - ALPHA) * a0.z * nv + ALPHA * hv.z;
    r.w = (1.0f - ALPHA) * a0.w * nv + ALPHA * hv.w;

    if (MODE == 0) {
        half4 w;
        w.a = __floats2half2_rn(r.x * nv, r.y * nv);
        w.b = __floats2half2_rn(r.z * nv, r.w * nv);
        outp[o] = w;
    } else if (MODE == 1) {
        float4 b = b2v[lane];
        float4 x;
        x.x = eluf(r.x + b.x); x.y = eluf(r.y + b.y);
        x.z = eluf(r.z + b.z); x.w = eluf(r.w + b.w);
        x0out[o] = x;
        half4 w;
        w.a = __floats2half2_rn(x.x * nv, x.y * nv);
        w.b = __floats2half2_rn(x.z * nv, x.w * nv);
        outp[o] = w;
    } else {
        outf[o] = make_float4(eluf(r.x), eluf(r.y), eluf(r.z), eluf(r.w));
    }
}

// ---------------- launch ----------------

extern "C" void kernel_launch(void* const* d_in, const int* in_sizes, int n_in,
                              void* d_out, int out_size, void* d_ws, size_t ws_size,
                              hipStream_t stream)
{
    const float* features = (const float*)d_in[0];
    const int*   src      = (const int*)d_in[1];
    const int*   dst      = (const int*)d_in[2];
    const float* W1       = (const float*)d_in[3];
    const float* b1       = (const float*)d_in[4];
    const float* W2       = (const float*)d_in[5];
    const float* b2       = (const float*)d_in[6];
    float* out = (float*)d_out;

    const int n  = in_sizes[0] / IN_DIM;   // 100000
    const int nE = in_sizes[1];            // 1600000

    // workspace layout:
    // f32:  nrm[n] | z0[16n] | x0[16n] | Wc[4096] | bc[16]
    // f16:  PH[16n] | QH[16n]
    // int:  deg[n] | off[n+4] | cursor[n] | bsum[1024] | csrc[nE]
    float* ws   = (float*)d_ws;
    float* nrm  = ws;
    float* z0   = nrm + n;
    float* x0   = z0 + (size_t)CLS * n;
    float* Wc   = x0 + (size_t)CLS * n;
    float* bc   = Wc + CLS * IN_DIM;
    __half* PH  = (__half*)(bc + 16);
    __half* QH  = PH + (size_t)CLS * n;
    int*   deg    = (int*)(QH + (size_t)CLS * n);
    int*   off    = deg + n;
    int*   cursor = off + n + 4;
    int*   bsum   = cursor + n;
    int*   csrc   = bsum + 1024;

    const int B = 256;
    const int nb = (n + 1023) / 1024;

    // ---- degree, norm, CSR ----
    zero_int_kernel<<<(n + B - 1) / B, B, 0, stream>>>(deg, n);
    hist_kernel<<<(nE + B - 1) / B, B, 0, stream>>>(dst, deg, nE);
    norm_kernel<<<(n + B - 1) / B, B, 0, stream>>>(deg, nrm, n);
    scan1_kernel<<<nb, 256, 0, stream>>>(deg, bsum, n);
    scan2_kernel<<<1, 64, 0, stream>>>(bsum, off, nb, n);
    scan3_kernel<<<nb, 256, 0, stream>>>(deg, bsum, off, cursor, n);
    fill_kernel<<<(nE + B - 1) / B, B, 0, stream>>>(src, dst, cursor, csrc, nE);

    // ---- combined fc ----
    wc_kernel<<<CLS, 256, 0, stream>>>(W1, W2, b1, Wc, bc);
    fcz_kernel<<<(n + BM - 1) / BM, 256, 0, stream>>>(features, Wc, bc, nrm, z0, PH, n);

    dim3 gblk(4, 64);
    int ggrid = (n + 63) / 64;

    // ---- propagation 1 (teleport z0); last step fuses +b2, ELU ----
    __half* pa = PH; __half* pb = QH;
    for (int k = 0; k < K_STEPS; k++) {
        if (k < K_STEPS - 1)
            gatherh_kernel<0><<<ggrid, gblk, 0, stream>>>(
                off, csrc, (const half4*)pa, (const float4*)z0, nrm,
                nullptr, (half4*)pb, nullptr, nullptr, n);
        else
            gatherh_kernel<1><<<ggrid, gblk, 0, stream>>>(
                off, csrc, (const half4*)pa, (const float4*)z0, nrm,
                (const float4*)b2, (half4*)pb, (float4*)x0, nullptr, n);
        __half* t = pa; pa = pb; pb = t;
    }

    // ---- propagation 2 (teleport x0); last step fuses ELU -> out ----
    for (int k = 0; k < K_STEPS; k++) {
        if (k < K_STEPS - 1)
            gatherh_kernel<0><<<ggrid, gblk, 0, stream>>>(
                off, csrc, (const half4*)pa, (const float4*)x0, nrm,
                nullptr, (half4*)pb, nullptr, nullptr, n);
        else
            gatherh_kernel<2><<<ggrid, gblk, 0, stream>>>(
                off, csrc, (const half4*)pa, (const float4*)x0, nrm,
                nullptr, nullptr, nullptr, (float4*)out, n);
        __half* t = pa; pa = pb; pb = t;
    }
}